// Round 1
// baseline (191.944 us; speedup 1.0000x reference)
//
#include <hip/hip_runtime.h>

#define B_SZ 1024
#define DIN 512
#define HH 512   // H
#define DOUT 512

// ---------------------------------------------------------------------------
// prep: wb[i][j] = (j>i) ? {W_hh[i][j], b_hh[i][j]} : {0, -1}
// (w=0,b=-1 -> relu(h*0-1)=0 -> contrib 0; removes mask from hot loop)
// ---------------------------------------------------------------------------
__global__ __launch_bounds__(256)
void prep_kernel(const float* __restrict__ W_hh,
                 const float* __restrict__ b_hh,
                 float2* __restrict__ wb) {
    int idx = blockIdx.x * 256 + threadIdx.x;   // over (H-1)*H, exact grid
    int i = idx >> 9;          // / 512
    int j = idx & 511;         // % 512
    float2 o;
    if (j > i) { o.x = W_hh[idx]; o.y = b_hh[idx]; }
    else       { o.x = 0.0f;      o.y = -1.0f;     }
    wb[idx] = o;
}

// ---------------------------------------------------------------------------
// Tiled fp32 GEMM: C[M,N] = act(A[M,K] @ B[K,N] + bias), act = relu^2 or none
// BM=32, BN=64, BK=32, 256 threads, each thread 2x4 outputs.
// ---------------------------------------------------------------------------
template <bool ACT>
__global__ __launch_bounds__(256)
void gemm_kernel(const float* __restrict__ A,
                 const float* __restrict__ Bm,
                 const float* __restrict__ bias,
                 float* __restrict__ C,
                 int M, int N, int K) {
    __shared__ float As[32][34];   // [k][m], pad to even for aligned float2
    __shared__ float Bs[32][64];   // [k][n]

    const int tid = threadIdx.x;
    const int bm = blockIdx.x * 32;
    const int bn = blockIdx.y * 64;
    const int tx = tid & 15;    // col group (x4)
    const int ty = tid >> 4;    // row group (x2)

    float acc[2][4] = {{0.f,0.f,0.f,0.f},{0.f,0.f,0.f,0.f}};

    for (int kt = 0; kt < K; kt += 32) {
        // A tile: 32 rows x 32 k
        {
            const int r  = tid >> 3;         // 0..31
            const int k4 = (tid & 7) * 4;    // 0..28
            const float4 av = *(const float4*)&A[(size_t)(bm + r) * K + kt + k4];
            As[k4 + 0][r] = av.x;
            As[k4 + 1][r] = av.y;
            As[k4 + 2][r] = av.z;
            As[k4 + 3][r] = av.w;
        }
        // B tile: 32 k x 64 n
        {
            const int kr = tid >> 4;         // 0..15
            const int c4 = (tid & 15) * 4;   // 0..60
            *(float4*)&Bs[kr][c4]      = *(const float4*)&Bm[(size_t)(kt + kr) * N + bn + c4];
            *(float4*)&Bs[kr + 16][c4] = *(const float4*)&Bm[(size_t)(kt + kr + 16) * N + bn + c4];
        }
        __syncthreads();

        #pragma unroll
        for (int k = 0; k < 32; ++k) {
            const float2 a  = *(const float2*)&As[k][ty * 2];
            const float4 b4 = *(const float4*)&Bs[k][tx * 4];
            acc[0][0] = fmaf(a.x, b4.x, acc[0][0]);
            acc[0][1] = fmaf(a.x, b4.y, acc[0][1]);
            acc[0][2] = fmaf(a.x, b4.z, acc[0][2]);
            acc[0][3] = fmaf(a.x, b4.w, acc[0][3]);
            acc[1][0] = fmaf(a.y, b4.x, acc[1][0]);
            acc[1][1] = fmaf(a.y, b4.y, acc[1][1]);
            acc[1][2] = fmaf(a.y, b4.z, acc[1][2]);
            acc[1][3] = fmaf(a.y, b4.w, acc[1][3]);
        }
        __syncthreads();
    }

    // epilogue: bias (+ relu^2), vectorized store
    #pragma unroll
    for (int r = 0; r < 2; ++r) {
        const int row = bm + ty * 2 + r;
        const int col = bn + tx * 4;
        float4 v;
        v.x = acc[r][0] + bias[col + 0];
        v.y = acc[r][1] + bias[col + 1];
        v.z = acc[r][2] + bias[col + 2];
        v.w = acc[r][3] + bias[col + 3];
        if (ACT) {
            v.x = fmaxf(v.x, 0.f); v.x *= v.x;
            v.y = fmaxf(v.y, 0.f); v.y *= v.y;
            v.z = fmaxf(v.z, 0.f); v.z *= v.z;
            v.w = fmaxf(v.w, 0.f); v.w *= v.w;
        }
        *(float4*)&C[(size_t)row * N + col] = v;
    }
}

// ---------------------------------------------------------------------------
// Sequential triangular scan. One wave per batch row. Lane l holds columns
// l + 64k, k=0..7. i-loop chunked by 64 so the broadcast source register is
// compile-time; broadcast via v_readlane (uniform lane index). Ping-pong
// register prefetch of the next step's weights.
// ---------------------------------------------------------------------------
__global__ __launch_bounds__(256)
void scan_kernel(const float2* __restrict__ wb, float* __restrict__ h) {
    const int lane = threadIdx.x & 63;
    const int wave = threadIdx.x >> 6;
    const int row  = blockIdx.x * 4 + wave;   // 256 blocks x 4 waves = 1024 rows
    float* hrow = h + (size_t)row * HH;

    float hr[8];
    #pragma unroll
    for (int k = 0; k < 8; ++k) hr[k] = hrow[lane + 64 * k];

    #pragma unroll
    for (int c = 0; c < 8; ++c) {
        const int base = 64 * c;
        const int nsteps = (c == 7) ? 63 : 64;
        float2 bufA[8], bufB[8];

        auto ld = [&](int i, float2* buf) {
            if (i <= 510) {
                #pragma unroll
                for (int k = c; k < 8; ++k)
                    buf[k] = wb[(size_t)i * HH + lane + 64 * k];
            }
        };
        auto cmp = [&](int ii, const float2* buf) {
            const float hi = __uint_as_float(
                __builtin_amdgcn_readlane(__float_as_uint(hr[c]), ii));
            #pragma unroll
            for (int k = c; k < 8; ++k) {
                float t = fmaf(hi, buf[k].x, buf[k].y);
                float r = fmaxf(t, 0.f);
                hr[k] = fmaf(r, r, hr[k]);
            }
        };

        ld(base, bufA);
        for (int ii = 0; ii < nsteps; ii += 2) {
            ld(base + ii + 1, bufB);
            cmp(ii, bufA);
            ld(base + ii + 2, bufA);
            if (ii + 1 < nsteps) cmp(ii + 1, bufB);
        }
    }

    #pragma unroll
    for (int k = 0; k < 8; ++k) hrow[lane + 64 * k] = hr[k];
}

// ---------------------------------------------------------------------------
extern "C" void kernel_launch(void* const* d_in, const int* in_sizes, int n_in,
                              void* d_out, int out_size, void* d_ws, size_t ws_size,
                              hipStream_t stream) {
    const float* x     = (const float*)d_in[0];
    const float* W_in  = (const float*)d_in[1];
    const float* b_in  = (const float*)d_in[2];
    const float* W_hh  = (const float*)d_in[3];
    const float* b_hh  = (const float*)d_in[4];
    const float* W_out = (const float*)d_in[5];
    const float* b_out = (const float*)d_in[6];
    float* out = (float*)d_out;

    // workspace layout: [0, 2MB) wb (511*512 float2), [2MB, 4MB) h
    float2* wb = (float2*)d_ws;
    float*  h  = (float*)((char*)d_ws + (1u << 21));

    // 1) masked interleaved weights: (H-1)*H = 261632 elems = 1022 * 256
    prep_kernel<<<dim3(1022), dim3(256), 0, stream>>>(W_hh, b_hh, wb);

    // 2) h0 = relu^2(x @ W_in + b_in)
    gemm_kernel<true><<<dim3(B_SZ / 32, HH / 64), dim3(256), 0, stream>>>(
        x, W_in, b_in, h, B_SZ, HH, DIN);

    // 3) sequential triangular scan, in-place on h
    scan_kernel<<<dim3(256), dim3(256), 0, stream>>>(wb, h);

    // 4) out = h @ W_out + b_out
    gemm_kernel<false><<<dim3(B_SZ / 32, DOUT / 64), dim3(256), 0, stream>>>(
        h, W_out, b_out, out, B_SZ, DOUT, HH);
}

// Round 2
// 167.335 us; speedup vs baseline: 1.1471x; 1.1471x over previous
//
#include <hip/hip_runtime.h>

#define B_SZ 1024
#define DIN 512
#define HH 512   // H
#define DOUT 512

// ---------------------------------------------------------------------------
// prep: wb[i][j] = (j>i) ? {W_hh[i][j], b_hh[i][j]} : {0, -1}
// (w=0,b=-1 -> relu(h*0-1)=0 -> contrib 0; removes mask from hot loop)
// ---------------------------------------------------------------------------
__global__ __launch_bounds__(256)
void prep_kernel(const float* __restrict__ W_hh,
                 const float* __restrict__ b_hh,
                 float2* __restrict__ wb) {
    int idx = blockIdx.x * 256 + threadIdx.x;   // over (H-1)*H, exact grid
    int i = idx >> 9;          // / 512
    int j = idx & 511;         // % 512
    float2 o;
    if (j > i) { o.x = W_hh[idx]; o.y = b_hh[idx]; }
    else       { o.x = 0.0f;      o.y = -1.0f;     }
    wb[idx] = o;
}

// ---------------------------------------------------------------------------
// Tiled fp32 GEMM with register-relay double buffer.
// C[M,N] = act(A[M,K] @ B[K,N] + bias), act = relu^2 or none
// BM=32, BN=64, BK=32, 256 threads, 2x4 microtile. Grid 256 blocks (1/CU).
// Next tile's global loads are issued BEFORE the compute loop and pinned
// there with sched_barrier(0) so L2 latency overlaps the 32-step FMA loop.
// ---------------------------------------------------------------------------
template <bool ACT>
__global__ __launch_bounds__(256)
void gemm_kernel(const float* __restrict__ A,
                 const float* __restrict__ Bm,
                 const float* __restrict__ bias,
                 float* __restrict__ C,
                 int M, int N, int K) {
    __shared__ float As[32][34];   // [k][m], pad->8B-aligned float2 reads
    __shared__ float Bs[32][64];   // [k][n]

    const int tid = threadIdx.x;
    const int bm = blockIdx.x * 32;
    const int bn = blockIdx.y * 64;
    const int tx = tid & 15;       // col group (x4)
    const int ty = tid >> 4;       // row group (x2)
    const int ar = tid >> 3;       // A stage: row 0..31
    const int ak = (tid & 7) * 4;  // A stage: k 0..28
    const int bk = tid >> 4;       // B stage: k 0..15
    const int bc = (tid & 15) * 4; // B stage: col 0..60

    float4 av, bv0, bv1;           // relay registers

    auto stage = [&](int kt) {
        av  = *(const float4*)&A[(size_t)(bm + ar) * K + kt + ak];
        bv0 = *(const float4*)&Bm[(size_t)(kt + bk) * N + bn + bc];
        bv1 = *(const float4*)&Bm[(size_t)(kt + bk + 16) * N + bn + bc];
    };

    float acc[2][4] = {{0.f,0.f,0.f,0.f},{0.f,0.f,0.f,0.f}};

    stage(0);
    for (int kt = 0; kt < K; kt += 32) {
        __syncthreads();
        As[ak + 0][ar] = av.x;
        As[ak + 1][ar] = av.y;
        As[ak + 2][ar] = av.z;
        As[ak + 3][ar] = av.w;
        *(float4*)&Bs[bk][bc]      = bv0;
        *(float4*)&Bs[bk + 16][bc] = bv1;
        __syncthreads();
        if (kt + 32 < K) stage(kt + 32);      // prefetch next tile into regs
        __builtin_amdgcn_sched_barrier(0);    // pin loads above the FMAs

        #pragma unroll
        for (int k = 0; k < 32; ++k) {
            const float2 a  = *(const float2*)&As[k][ty * 2];
            const float4 b4 = *(const float4*)&Bs[k][tx * 4];
            acc[0][0] = fmaf(a.x, b4.x, acc[0][0]);
            acc[0][1] = fmaf(a.x, b4.y, acc[0][1]);
            acc[0][2] = fmaf(a.x, b4.z, acc[0][2]);
            acc[0][3] = fmaf(a.x, b4.w, acc[0][3]);
            acc[1][0] = fmaf(a.y, b4.x, acc[1][0]);
            acc[1][1] = fmaf(a.y, b4.y, acc[1][1]);
            acc[1][2] = fmaf(a.y, b4.z, acc[1][2]);
            acc[1][3] = fmaf(a.y, b4.w, acc[1][3]);
        }
    }

    #pragma unroll
    for (int r = 0; r < 2; ++r) {
        const int row = bm + ty * 2 + r;
        const int col = bn + tx * 4;
        float4 v;
        v.x = acc[r][0] + bias[col + 0];
        v.y = acc[r][1] + bias[col + 1];
        v.z = acc[r][2] + bias[col + 2];
        v.w = acc[r][3] + bias[col + 3];
        if (ACT) {
            v.x = fmaxf(v.x, 0.f); v.x *= v.x;
            v.y = fmaxf(v.y, 0.f); v.y *= v.y;
            v.z = fmaxf(v.z, 0.f); v.z *= v.z;
            v.w = fmaxf(v.w, 0.f); v.w *= v.w;
        }
        *(float4*)&C[(size_t)row * N + col] = v;
    }
}

// ---------------------------------------------------------------------------
// Sequential triangular scan, v2: LDS-staged, register-relay pipelined.
// 256 blocks x 4 waves; wave w handles batch row blockIdx*4+w; lane l owns
// columns l+64k. Chunk C covers steps [64C, 64C+64) and columns [64C, 512).
// Per chunk, weights are staged tile-by-tile through 32 KB LDS shared by all
// 4 waves; the next tile's global loads sit in relay regs during compute.
// ---------------------------------------------------------------------------
template <int C>
__device__ __forceinline__ void scan_chunk(const float2* __restrict__ wb,
                                           float2* __restrict__ smem,
                                           float hr[8], int lane) {
    constexpr int W2 = 64 * (8 - C);                         // active cols
    constexpr int T  = (C < 4) ? 8 : (C < 6 ? 16 : (C == 6 ? 32 : 64));
    constexpr int NTILES = 64 / T;
    constexpr int NLD = (T * W2) / 256;                      // relay elems
    const int tid = threadIdx.x;

    float2 R[16];

    auto stage = [&](int i0) {
        #pragma unroll
        for (int q = 0; q < NLD; ++q) {
            const int e = tid + 256 * q;
            const int r = e / W2;              // const divide -> magic mul
            const int col = e - r * W2;
            int row = i0 + r;
            if (row > 510) row = 510;          // only chunk 7's pad row
            R[q] = wb[(size_t)row * HH + 64 * C + col];
        }
    };

    stage(64 * C);                             // preload tile 0
    for (int t = 0; t < NTILES; ++t) {
        __syncthreads();                       // LDS free (prev compute done)
        #pragma unroll
        for (int q = 0; q < NLD; ++q) smem[tid + 256 * q] = R[q];
        __syncthreads();                       // LDS tile ready
        if (t + 1 < NTILES) stage(64 * C + (t + 1) * T);
        __builtin_amdgcn_sched_barrier(0);     // pin prefetch above compute

        #pragma unroll 4
        for (int r = 0; r < T; ++r) {
            const int ii = t * T + r;          // step within chunk (uniform)
            if (C == 7 && ii == 63) break;     // no step 511
            const float hi = __uint_as_float(
                __builtin_amdgcn_readlane(__float_as_uint(hr[C]), ii));
            #pragma unroll
            for (int k = C; k < 8; ++k) {
                const float2 wv = smem[r * W2 + lane + 64 * (k - C)];
                const float tv = fmaf(hi, wv.x, wv.y);
                const float rv = fmaxf(tv, 0.f);
                hr[k] = fmaf(rv, rv, hr[k]);
            }
        }
    }
}

__global__ __launch_bounds__(256)
void scan_kernel(const float2* __restrict__ wb, float* __restrict__ h) {
    __shared__ float2 smem[4096];              // 32 KB, reused per tile
    const int lane = threadIdx.x & 63;
    const int wave = threadIdx.x >> 6;
    const int row  = blockIdx.x * 4 + wave;    // 256 blocks x 4 waves
    float* hrow = h + (size_t)row * HH;

    float hr[8];
    #pragma unroll
    for (int k = 0; k < 8; ++k) hr[k] = hrow[lane + 64 * k];

    scan_chunk<0>(wb, smem, hr, lane);
    scan_chunk<1>(wb, smem, hr, lane);
    scan_chunk<2>(wb, smem, hr, lane);
    scan_chunk<3>(wb, smem, hr, lane);
    scan_chunk<4>(wb, smem, hr, lane);
    scan_chunk<5>(wb, smem, hr, lane);
    scan_chunk<6>(wb, smem, hr, lane);
    scan_chunk<7>(wb, smem, hr, lane);

    #pragma unroll
    for (int k = 0; k < 8; ++k) hrow[lane + 64 * k] = hr[k];
}

// ---------------------------------------------------------------------------
extern "C" void kernel_launch(void* const* d_in, const int* in_sizes, int n_in,
                              void* d_out, int out_size, void* d_ws, size_t ws_size,
                              hipStream_t stream) {
    const float* x     = (const float*)d_in[0];
    const float* W_in  = (const float*)d_in[1];
    const float* b_in  = (const float*)d_in[2];
    const float* W_hh  = (const float*)d_in[3];
    const float* b_hh  = (const float*)d_in[4];
    const float* W_out = (const float*)d_in[5];
    const float* b_out = (const float*)d_in[6];
    float* out = (float*)d_out;

    // workspace layout: [0, 2MB) wb (511*512 float2), [2MB, 4MB) h
    float2* wb = (float2*)d_ws;
    float*  h  = (float*)((char*)d_ws + (1u << 21));

    // 1) masked interleaved weights: (H-1)*H = 261632 elems = 1022 * 256
    prep_kernel<<<dim3(1022), dim3(256), 0, stream>>>(W_hh, b_hh, wb);

    // 2) h0 = relu^2(x @ W_in + b_in)
    gemm_kernel<true><<<dim3(B_SZ / 32, HH / 64), dim3(256), 0, stream>>>(
        x, W_in, b_in, h, B_SZ, HH, DIN);

    // 3) sequential triangular scan, in-place on h
    scan_kernel<<<dim3(256), dim3(256), 0, stream>>>(wb, h);

    // 4) out = h @ W_out + b_out
    gemm_kernel<false><<<dim3(B_SZ / 32, DOUT / 64), dim3(256), 0, stream>>>(
        h, W_out, b_out, out, B_SZ, DOUT, HH);
}